// Round 8
// baseline (482.470 us; speedup 1.0000x reference)
//
#include <hip/hip_runtime.h>

#define BB 64
#define HH 512
#define WW 512
#define PLANE (HH * WW)
#define TS 64
#define N_CHEBY 15

struct R6 { float lf, a, b, c, d, rt; };

// lane i <- lane i-1 within 16-lane DPP row, boundary lanes get 0
__device__ __forceinline__ float dpp_from_left(float x) {
    return __int_as_float(__builtin_amdgcn_update_dpp(
        0, __float_as_int(x), 0x111, 0xF, 0xF, true));   // row_shr:1
}
// lane i <- lane i+1, boundary lanes get 0
__device__ __forceinline__ float dpp_from_right(float x) {
    return __int_as_float(__builtin_amdgcn_update_dpp(
        0, __float_as_int(x), 0x101, 0xF, 0xF, true));   // row_shl:1
}

__device__ __forceinline__ R6 ldrow(const float* rowp, int cg) {
    const float4 v = *reinterpret_cast<const float4*>(rowp + (cg << 2));
    R6 r;
    r.a = v.x; r.b = v.y; r.c = v.z; r.d = v.w;
    r.lf = dpp_from_left(v.w);   // col 4cg-1 (0 at tile edge -> halo-invalid anyway)
    r.rt = dpp_from_right(v.x);  // col 4cg+4
    return r;
}

__device__ __forceinline__ void racc6(const R6& r, float k0, float k1, float k2,
                                      float4& o) {
    o.x = fmaf(k0, r.lf, fmaf(k1, r.a, fmaf(k2, r.b, o.x)));
    o.y = fmaf(k0, r.a,  fmaf(k1, r.b, fmaf(k2, r.c, o.y)));
    o.z = fmaf(k0, r.b,  fmaf(k1, r.c, fmaf(k2, r.d, o.z)));
    o.w = fmaf(k0, r.c,  fmaf(k1, r.d, fmaf(k2, r.rt, o.w)));
}

// ---------------------------------------------------------------------------
// Square-tile temporal blocking: load 64x64 tile into LDS, apply stencil F
// times (ping-pong, 1 barrier/level), store interior OUT=64-2F square.
// conv (CHEBY=false): v1 = invv*A(in), v_{j+1} = A(v_j); tracks interior
//   max|v_{F-1}| (pmz) and max|v_F| (pmw).
// cheby (CHEBY=true): x_{j+1} = x_j + tau_j*(f - A x_j), f held in registers.
// ---------------------------------------------------------------------------
template<int F, bool CHEBY, bool STORE, int NPREV>
__global__ __launch_bounds__(256, 4) void tile_pass(
    const float* __restrict__ in, const float* __restrict__ fin,
    const float* __restrict__ kern, const float* __restrict__ pm_prev,
    const float* __restrict__ taus, int taubase,
    float* __restrict__ outp, float* __restrict__ pmw, float* __restrict__ pmz)
{
    constexpr int OUT = TS - 2 * F;
    constexpr int NT  = (WW + OUT - 1) / OUT;

    __shared__ float buf[2][TS + 2][TS];   // guard rows 0 and TS+1 stay zero
    __shared__ float sred[8];

    const int t = threadIdx.x, cg = t & 15, rb = t >> 4;
    const int b = blockIdx.y, tile = blockIdx.x;
    const int ti = tile % NT, tj = tile / NT;
    const int gx0 = min(ti * OUT, WW - OUT), gy0 = min(tj * OUT, HH - OUT);
    const int ox = gx0 - F, oy = gy0 - F;

    // zero guard rows of both buffers (one write per thread)
    { const int p = (t >> 7) & 1, rr = ((t >> 6) & 1) ? (TS + 1) : 0;
      buf[p][rr][t & 63] = 0.f; }

    // reduce previous pass's per-tile maxima -> 1/m
    if (NPREV > 0) {
        float v = (t < NPREV) ? pm_prev[b * NPREV + t] : 0.f;
#pragma unroll
        for (int o = 32; o; o >>= 1) v = fmaxf(v, __shfl_xor(v, o, 64));
        if ((t & 63) == 0) sred[t >> 6] = v;
    }

    // tile load (zero-filled outside plane)
    const float* ip = in + (size_t)b * PLANE;
#pragma unroll
    for (int k = 0; k < 16; ++k) {
        const int idx = (k << 8) + t, r = idx >> 6, c = idx & 63;
        const int gr = oy + r, gc = ox + c;
        const bool ok = ((unsigned)gr < HH) && ((unsigned)gc < WW);
        const int a = ok ? (gr * WW + gc) : 0;
        const float v = ip[a];
        buf[0][r + 1][c] = ok ? v : 0.f;
    }

    // f values for this thread's 16 fixed cells (cheby only)
    float fr[4][4];
    if (CHEBY) {
        const float* fp = fin + (size_t)b * PLANE;
#pragma unroll
        for (int cr = 0; cr < 4; ++cr) {
            const int gr = oy + (rb << 2) + cr;
#pragma unroll
            for (int jj = 0; jj < 4; ++jj) {
                const int gc = ox + (cg << 2) + jj;
                const bool ok = ((unsigned)gr < HH) && ((unsigned)gc < WW);
                const int a = ok ? (gr * WW + gc) : 0;
                const float v = fp[a];
                fr[cr][jj] = ok ? v : 0.f;
            }
        }
    }

    const float* kb = kern + b * 9;
    const float k00=kb[0],k01=kb[1],k02=kb[2],k10=kb[3],k11=kb[4],k12=kb[5],
                k20=kb[6],k21=kb[7],k22=kb[8];

    // plane masks (edge tiles only) and interior flags
    const bool edge = (ox < 0) || (oy < 0) || (ox + TS > WW) || (oy + TS > HH);
    float mr[4], mc[4];
    bool irow[4], icol[4]; float icolm[4];
#pragma unroll
    for (int cr = 0; cr < 4; ++cr) {
        mr[cr] = ((unsigned)(oy + (rb << 2) + cr) < HH) ? 1.f : 0.f;
        irow[cr] = (unsigned)((rb << 2) + cr - F) < (unsigned)OUT;
    }
#pragma unroll
    for (int jj = 0; jj < 4; ++jj) {
        mc[jj] = ((unsigned)(ox + (cg << 2) + jj) < WW) ? 1.f : 0.f;
        icol[jj] = (unsigned)((cg << 2) + jj - F) < (unsigned)OUT;
        icolm[jj] = icol[jj] ? 1.f : 0.f;
    }

    __syncthreads();
    float invv = 1.f;
    if (NPREV > 0)
        invv = 1.f / fmaxf(fmaxf(sred[0], sred[1]), fmaxf(sred[2], sred[3]));

    float mzv = 0.f, mwv = 0.f;
    float* op = outp ? outp + (size_t)b * PLANE : nullptr;

#pragma unroll 2
    for (int j = 0; j < F; ++j) {
        const float (*src)[TS] = buf[j & 1];
        float (*dst)[TS] = buf[(j & 1) ^ 1];
        const float tauj = CHEBY ? taus[(size_t)(taubase + j) * BB + b] : 0.f;

        R6 r0 = ldrow(&src[(rb << 2) + 0][0], cg);
        R6 r1 = ldrow(&src[(rb << 2) + 1][0], cg);
#pragma unroll
        for (int cr = 0; cr < 4; ++cr) {
            R6 r2 = ldrow(&src[(rb << 2) + 2 + cr][0], cg);
            float4 s = make_float4(0.f, 0.f, 0.f, 0.f);
            racc6(r0, k00, k01, k02, s);
            racc6(r1, k10, k11, k12, s);
            racc6(r2, k20, k21, k22, s);
            float4 o;
            if (CHEBY) {
                o.x = fmaf(tauj, fr[cr][0] - s.x, r1.a);
                o.y = fmaf(tauj, fr[cr][1] - s.y, r1.b);
                o.z = fmaf(tauj, fr[cr][2] - s.z, r1.c);
                o.w = fmaf(tauj, fr[cr][3] - s.w, r1.d);
            } else if (NPREV > 0 && j == 0) {
                o.x = s.x * invv; o.y = s.y * invv;
                o.z = s.z * invv; o.w = s.w * invv;
            } else {
                o = s;
            }
            if (edge) {   // zero-padding semantics for out-of-plane cells
                const float m = mr[cr];
                o.x *= m * mc[0]; o.y *= m * mc[1];
                o.z *= m * mc[2]; o.w *= m * mc[3];
            }
            if (!CHEBY && j == F - 2) {
                const float m4 = fmaxf(
                    fmaxf(fabsf(o.x) * icolm[0], fabsf(o.y) * icolm[1]),
                    fmaxf(fabsf(o.z) * icolm[2], fabsf(o.w) * icolm[3]));
                mzv = fmaxf(mzv, irow[cr] ? m4 : 0.f);
            }
            if (j == F - 1) {
                if (!CHEBY) {
                    const float m4 = fmaxf(
                        fmaxf(fabsf(o.x) * icolm[0], fabsf(o.y) * icolm[1]),
                        fmaxf(fabsf(o.z) * icolm[2], fabsf(o.w) * icolm[3]));
                    mwv = fmaxf(mwv, irow[cr] ? m4 : 0.f);
                }
                if (STORE && irow[cr]) {
                    const int gr = oy + (rb << 2) + cr;
                    float* orow = op + (size_t)gr * WW + ox + (cg << 2);
                    if (icol[0]) orow[0] = o.x;
                    if (icol[1]) orow[1] = o.y;
                    if (icol[2]) orow[2] = o.z;
                    if (icol[3]) orow[3] = o.w;
                }
            } else {
                *reinterpret_cast<float4*>(&dst[(rb << 2) + 1 + cr][cg << 2]) = o;
            }
            r0 = r1; r1 = r2;
        }
        if (j != F - 1) __syncthreads();
    }

    if (!CHEBY) {
        __syncthreads();
#pragma unroll
        for (int o = 32; o; o >>= 1) {
            mzv = fmaxf(mzv, __shfl_xor(mzv, o, 64));
            mwv = fmaxf(mwv, __shfl_xor(mwv, o, 64));
        }
        if ((t & 63) == 0) { sred[t >> 6] = mzv; sred[4 + (t >> 6)] = mwv; }
        __syncthreads();
        if (t == 0) {
            pmz[b * NT * NT + tile] =
                fmaxf(fmaxf(sred[0], sred[1]), fmaxf(sred[2], sred[3]));
            pmw[b * NT * NT + tile] =
                fmaxf(fmaxf(sred[4], sred[5]), fmaxf(sred[6], sred[7]));
        }
    }
}

// m = max|v20| / max|v19|; taus[it*BB+b]
__global__ __launch_bounds__(256) void tau_k(
    const float* __restrict__ pmz, const float* __restrict__ pmw,
    float* __restrict__ taus, int n)
{
    __shared__ float sred[8];
    const int b = blockIdx.x, t = threadIdx.x;
    float vz = (t < n) ? pmz[b * n + t] : 0.f;
    float vw = (t < n) ? pmw[b * n + t] : 0.f;
#pragma unroll
    for (int o = 32; o; o >>= 1) {
        vz = fmaxf(vz, __shfl_xor(vz, o, 64));
        vw = fmaxf(vw, __shfl_xor(vw, o, 64));
    }
    if ((t & 63) == 0) { sred[t >> 6] = vz; sred[4 + (t >> 6)] = vw; }
    __syncthreads();
    if (t < N_CHEBY) {
        const float mz = fmaxf(fmaxf(sred[0], sred[1]), fmaxf(sred[2], sred[3]));
        const float mw = fmaxf(fmaxf(sred[4], sred[5]), fmaxf(sred[6], sred[7]));
        const float m = mw / mz;
        const double rr = cos(M_PI * (2.0 * t + 1.0) / (2.0 * N_CHEBY));
        const float denom = m + m / 3.0f - (m / 3.0f - m) * (float)rr;
        taus[t * BB + b] = 2.0f / denom;
    }
}

extern "C" void kernel_launch(void* const* d_in, const int* in_sizes, int n_in,
                              void* d_out, int out_size, void* d_ws, size_t ws_size,
                              hipStream_t stream)
{
    const float* x_in = (const float*)d_in[0];
    const float* f_in = (const float*)d_in[1];
    const float* k_in = (const float*)d_in[2];
    const float* u_in = (const float*)d_in[3];
    float* out = (float*)d_out;

    float* bufA = (float*)d_ws;                 // 64 MB scratch field
    float* pmW0 = bufA + (size_t)BB * PLANE;    // [BB*144]
    float* pmW1 = pmW0 + BB * 144;
    float* pmZ  = pmW1 + BB * 144;
    float* taus = pmZ  + BB * 144;              // [15*BB]

    dim3 blk(256);

    // ---- power iteration: 2 passes of F=10 (OUT=44, NT=12, 144 tiles) ----
    tile_pass<10, false, true, 0><<<dim3(144, BB), blk, 0, stream>>>(
        u_in, nullptr, k_in, nullptr, nullptr, 0, bufA, pmW0, pmZ);
    tile_pass<10, false, false, 144><<<dim3(144, BB), blk, 0, stream>>>(
        bufA, nullptr, k_in, pmW0, nullptr, 0, nullptr, pmW1, pmZ);

    tau_k<<<BB, 256, 0, stream>>>(pmZ, pmW1, taus, 144);

    // ---- Chebyshev: F=8 (OUT=48, 121 tiles) then F=7 (OUT=50, 121 tiles) ----
    tile_pass<8, true, true, 0><<<dim3(121, BB), blk, 0, stream>>>(
        x_in, f_in, k_in, nullptr, taus, 0, bufA, nullptr, nullptr);
    tile_pass<7, true, true, 0><<<dim3(121, BB), blk, 0, stream>>>(
        bufA, f_in, k_in, nullptr, taus, 8, out, nullptr, nullptr);
}

// Round 9
// 450.255 us; speedup vs baseline: 1.0715x; 1.0715x over previous
//
#include <hip/hip_runtime.h>

#define BB 64
#define HH 512
#define WW 512
#define PLANE (HH * WW)
#define N_CHEBY 15

struct Sl { float a, b, c, d; };

__device__ __forceinline__ void racc(const Sl& s, float k0, float k1, float k2,
                                     float& o0, float& o1) {
    o0 = fmaf(k0, s.a, fmaf(k1, s.b, fmaf(k2, s.c, o0)));
    o1 = fmaf(k0, s.b, fmaf(k1, s.c, fmaf(k2, s.d, o1)));
}

__device__ __forceinline__ Sl ldsl(const float* pl, int row, int c2, bool ok) {
    Sl s = {0.f, 0.f, 0.f, 0.f};
    if (ok) {
        const float* rp = pl + (size_t)row * WW;
        float2 v = *reinterpret_cast<const float2*>(rp + c2);
        s.b = v.x; s.c = v.y;
        if (c2 > 0)      s.a = rp[c2 - 1];
        if (c2 + 2 < WW) s.d = rp[c2 + 2];
    }
    return s;
}

// Barrier WITHOUT vmcnt drain: flush LDS ops, leave global loads in flight.
__device__ __forceinline__ void softbar() {
    __asm__ volatile("s_waitcnt lgkmcnt(0)" ::: "memory");
    __builtin_amdgcn_s_barrier();
}

// ---------------------------------------------------------------------------
// Fused FDv-level power pass (row-march, stripe height RR). Proven round-7.
// v1 = inv*A(in), v_{j+1} = A(v_j); mz = stripe max|v_{FDv-1}|, mw = max|v_FDv|.
// ---------------------------------------------------------------------------
template<int FDv, int RR>
__global__ __launch_bounds__(256, 2) void conv_fusedN(
    const float* __restrict__ in, const float* __restrict__ kern,
    const float* __restrict__ pm_prev, float* __restrict__ out,
    float* __restrict__ pmw, float* __restrict__ pmz)
{
    constexpr int NS = HH / RR;
    const int b = blockIdx.y, stripe = blockIdx.x, ytop = stripe * RR;
    const int t = threadIdx.x, c2 = t << 1;

    __shared__ float re[FDv - 1][2][258], ro[FDv - 1][2][258];
    __shared__ float sred[8];
    __shared__ float sinv;

    if (t < 2 * (FDv - 1)) {
        const int l = t >> 1, par = t & 1;
        re[l][par][0] = 0.f; re[l][par][257] = 0.f;
        ro[l][par][0] = 0.f; ro[l][par][257] = 0.f;
    }
    if (pm_prev && t < 64) {
        float v = (t < NS) ? pm_prev[b * NS + t] : 0.f;
#pragma unroll
        for (int o = 8; o; o >>= 1) v = fmaxf(v, __shfl_xor(v, o, 64));
        if (t == 0) sinv = 1.f / v;
    }
    __syncthreads();
    const float invv = pm_prev ? sinv : 1.f;

    const float* kb = kern + b * 9;
    const float k00=kb[0],k01=kb[1],k02=kb[2],k10=kb[3],k11=kb[4],k12=kb[5],
                k20=kb[6],k21=kb[7],k22=kb[8];
    const float* ip = in + (size_t)b * PLANE;
    float* op = out ? out + (size_t)b * PLANE : nullptr;

    Sl u2 = {0,0,0,0}, u1 = {0,0,0,0};
    Sl ltp[FDv - 1], lmd[FDv - 1];
    float own0[FDv - 1], own1[FDv - 1];
#pragma unroll
    for (int l = 0; l < FDv - 1; ++l) {
        ltp[l] = Sl{0,0,0,0}; lmd[l] = Sl{0,0,0,0};
        own0[l] = 0.f; own1[l] = 0.f;
    }
    float mz = 0.f, mw = 0.f;
    Sl u0 = ldsl(ip, ytop - FDv, c2, (unsigned)(ytop - FDv) < HH);

    const int STEPS   = RR + 3 * FDv - 1;
    const int LOADCUT = RR + 2 * FDv - 1;
#pragma unroll 2
    for (int p = 0; p < STEPS; ++p) {
        const int yu = ytop - FDv + p;
        Sl un = ldsl(ip, yu + 1, c2, ((unsigned)(yu + 1) < HH) && (p < LOADCUT));

        const int rpar = (p + 1) & 1, wpar = p & 1;
        Sl am[FDv - 1];
#pragma unroll
        for (int l = 0; l < FDv - 1; ++l) {
            am[l].a = ro[l][rpar][t];
            am[l].b = own0[l];
            am[l].c = own1[l];
            am[l].d = re[l][rpar][2 + t];
        }

        float v0[FDv], v1[FDv];
        {   // level 1 (normalized)
            float s0 = 0.f, s1 = 0.f;
            racc(u2, k00,k01,k02, s0,s1);
            racc(u1, k10,k11,k12, s0,s1);
            racc(u0, k20,k21,k22, s0,s1);
            const int y = yu - 1;
            const bool act = (y >= ytop - (FDv-1)) && (y <= ytop + RR + FDv - 2)
                          && ((unsigned)y < HH);
            v0[0] = act ? s0 * invv : 0.f;
            v1[0] = act ? s1 * invv : 0.f;
        }
#pragma unroll
        for (int j = 2; j <= FDv; ++j) {
            float s0 = 0.f, s1 = 0.f;
            racc(ltp[j-2], k00,k01,k02, s0,s1);
            racc(lmd[j-2], k10,k11,k12, s0,s1);
            racc(am[j-2],  k20,k21,k22, s0,s1);
            const int y = yu - (2*j - 1);
            if (j < FDv) {
                const bool act = (y >= ytop - (FDv-j)) && (y <= ytop + RR + FDv - j - 1)
                              && ((unsigned)y < HH);
                v0[j-1] = act ? s0 : 0.f;
                v1[j-1] = act ? s1 : 0.f;
                if (j == FDv - 1)
                    mz = fmaxf(mz, fmaxf(fabsf(v0[j-1]), fabsf(v1[j-1])));
            } else {
                if (y >= ytop && y < ytop + RR) {
                    mw = fmaxf(mw, fmaxf(fabsf(s0), fabsf(s1)));
                    if (op)
                        *reinterpret_cast<float2*>(op + (size_t)y * WW + c2) =
                            make_float2(s0, s1);
                }
            }
        }
#pragma unroll
        for (int l = 0; l < FDv - 1; ++l) {
            re[l][wpar][1 + t] = v0[l];
            ro[l][wpar][1 + t] = v1[l];
            ltp[l] = lmd[l]; lmd[l] = am[l];
            own0[l] = v0[l]; own1[l] = v1[l];
        }
        u2 = u1; u1 = u0; u0 = un;
        softbar();
    }

#pragma unroll
    for (int o = 32; o; o >>= 1) {
        mz = fmaxf(mz, __shfl_xor(mz, o, 64));
        mw = fmaxf(mw, __shfl_xor(mw, o, 64));
    }
    if ((t & 63) == 0) { sred[t >> 6] = mz; sred[4 + (t >> 6)] = mw; }
    __syncthreads();
    if (t == 0) {
        pmz[b * NS + stripe] =
            fmaxf(fmaxf(sred[0], sred[1]), fmaxf(sred[2], sred[3]));
        pmw[b * NS + stripe] =
            fmaxf(fmaxf(sred[4], sred[5]), fmaxf(sred[6], sred[7]));
    }
}

// m = max|v20| / max|v19|; taus[it*BB+b].  (8 stripes from the conv passes)
__global__ __launch_bounds__(64) void tau_fused(
    const float* __restrict__ pmz, const float* __restrict__ pmw,
    float* __restrict__ taus)
{
    constexpr int NS = 8;
    const int b = blockIdx.x, t = threadIdx.x;
    float vz = (t < NS) ? pmz[b * NS + t] : 0.f;
    float vw = (t < NS) ? pmw[b * NS + t] : 0.f;
#pragma unroll
    for (int o = 8; o; o >>= 1) {
        vz = fmaxf(vz, __shfl_xor(vz, o, 64));
        vw = fmaxf(vw, __shfl_xor(vw, o, 64));
    }
    if (t < N_CHEBY) {
        const float m = vw / vz;
        const double rr = cos(M_PI * (2.0 * t + 1.0) / (2.0 * N_CHEBY));
        const float denom = m + m / 3.0f - (m / 3.0f - m) * (float)rr;
        taus[t * BB + b] = 2.0f / denom;
    }
}

// ---------------------------------------------------------------------------
// Fused FDv-level Chebyshev pass, R=32 stripes.
//  - f: 1-row lookahead register for level 1; levels 2..FDv reload from L2.
//  - packed float2 LDS rings (1 ds_write_b64 + 2 ds_read_b32 per level).
//  - steady-state steps run UNMASKED (validity cone proven); fill/drain and
//    plane-edge stripes use the masked step.
// ---------------------------------------------------------------------------
template<int FDv>
__global__ __launch_bounds__(256, 4) void cheby9(
    const float* __restrict__ xin, const float* __restrict__ fin,
    const float* __restrict__ kern, const float* __restrict__ tauv,
    float* __restrict__ xout)
{
    constexpr int RR = 32, NS = HH / RR;
    constexpr int STEPS   = RR + 3 * FDv - 1;
    constexpr int LOADCUT = RR + 2 * FDv - 1;
    constexpr int FILLEND = 3 * FDv - 4;

    const int b = blockIdx.y, stripe = blockIdx.x, ytop = stripe * RR;
    const int t = threadIdx.x, c2 = t << 1;

    __shared__ float2 rc[FDv - 1][2][258];
    if (t < 2 * (FDv - 1)) {
        const int l = t >> 1, par = t & 1;
        rc[l][par][0]   = make_float2(0.f, 0.f);
        rc[l][par][257] = make_float2(0.f, 0.f);
    }
    __syncthreads();

    const float* kb = kern + b * 9;
    const float k00=kb[0],k01=kb[1],k02=kb[2],k10=kb[3],k11=kb[4],k12=kb[5],
                k20=kb[6],k21=kb[7],k22=kb[8];
    float tau[FDv];
#pragma unroll
    for (int j = 0; j < FDv; ++j) tau[j] = tauv[j * BB + b];

    const float* xp = xin + (size_t)b * PLANE;
    const float* fp = fin + (size_t)b * PLANE;
    float* op = xout + (size_t)b * PLANE;

    Sl u2 = {0,0,0,0}, u1 = {0,0,0,0};
    Sl ltp[FDv - 1], lmd[FDv - 1];
    float own0[FDv - 1], own1[FDv - 1];
#pragma unroll
    for (int l = 0; l < FDv - 1; ++l) {
        ltp[l] = Sl{0,0,0,0}; lmd[l] = Sl{0,0,0,0};
        own0[l] = 0.f; own1[l] = 0.f;
    }

    Sl u0 = ldsl(xp, ytop - FDv, c2, (unsigned)(ytop - FDv) < HH);
    float2 fcur = make_float2(0.f, 0.f);
    {
        const int yf = ytop - FDv - 1;
        if ((unsigned)yf < HH)
            fcur = *reinterpret_cast<const float2*>(fp + (size_t)yf * WW + c2);
    }

    auto step = [&](const int p, const bool MASKED)
        __attribute__((always_inline))
    {
        const int yu = ytop - FDv + p;
        const bool ldok = (p < LOADCUT);
        Sl un = ldsl(xp, yu + 1, c2, ldok && (!MASKED || (unsigned)(yu + 1) < HH));
        float2 fn = make_float2(0.f, 0.f);
        if (ldok && (!MASKED || (unsigned)yu < HH))
            fn = *reinterpret_cast<const float2*>(fp + (size_t)yu * WW + c2);

        // per-level f rows (L2-resident re-reads)
        float2 fj[FDv - 1];
#pragma unroll
        for (int j = 2; j <= FDv; ++j) {
            const int yf = yu - (2 * j - 1);
            fj[j - 2] = make_float2(0.f, 0.f);
            if (!MASKED || (unsigned)yf < HH)
                fj[j - 2] = *reinterpret_cast<const float2*>(fp + (size_t)yf * WW + c2);
        }

        const int rpar = (p + 1) & 1, wpar = p & 1;
        Sl am[FDv - 1];
#pragma unroll
        for (int l = 0; l < FDv - 1; ++l) {
            const float* F = reinterpret_cast<const float*>(&rc[l][rpar][0]);
            am[l].a = F[2 * t + 1];
            am[l].b = own0[l];
            am[l].c = own1[l];
            am[l].d = F[2 * t + 4];
        }

        float v0[FDv - 1], v1[FDv - 1];
        {   // level 1: x1 = x + tau0*(f - A x) at row yu-1
            float s0 = 0.f, s1 = 0.f;
            racc(u2, k00,k01,k02, s0,s1);
            racc(u1, k10,k11,k12, s0,s1);
            racc(u0, k20,k21,k22, s0,s1);
            float nv0 = fmaf(tau[0], fcur.x - s0, u1.b);
            float nv1 = fmaf(tau[0], fcur.y - s1, u1.c);
            if (MASKED) {
                const int y = yu - 1;
                const bool act = (y >= ytop - (FDv-1)) && (y <= ytop + RR + FDv - 2)
                              && ((unsigned)y < HH);
                nv0 = act ? nv0 : 0.f;
                nv1 = act ? nv1 : 0.f;
            }
            v0[0] = nv0; v1[0] = nv1;
        }
#pragma unroll
        for (int j = 2; j <= FDv; ++j) {
            float s0 = 0.f, s1 = 0.f;
            racc(ltp[j-2], k00,k01,k02, s0,s1);
            racc(lmd[j-2], k10,k11,k12, s0,s1);
            racc(am[j-2],  k20,k21,k22, s0,s1);
            const int y = yu - (2 * j - 1);
            const float2 fv = fj[j - 2];
            if (j < FDv) {
                float nv0 = fmaf(tau[j-1], fv.x - s0, lmd[j-2].b);
                float nv1 = fmaf(tau[j-1], fv.y - s1, lmd[j-2].c);
                if (MASKED) {
                    const bool act = (y >= ytop - (FDv-j)) && (y <= ytop + RR + FDv - j - 1)
                                  && ((unsigned)y < HH);
                    nv0 = act ? nv0 : 0.f;
                    nv1 = act ? nv1 : 0.f;
                }
                v0[j-1] = nv0; v1[j-1] = nv1;
            } else {
                if (y >= ytop && y < ytop + RR) {
                    const float o0 = fmaf(tau[FDv-1], fv.x - s0, lmd[j-2].b);
                    const float o1 = fmaf(tau[FDv-1], fv.y - s1, lmd[j-2].c);
                    *reinterpret_cast<float2*>(op + (size_t)y * WW + c2) =
                        make_float2(o0, o1);
                }
            }
        }
#pragma unroll
        for (int l = 0; l < FDv - 1; ++l) {
            rc[l][wpar][1 + t] = make_float2(v0[l], v1[l]);
            ltp[l] = lmd[l]; lmd[l] = am[l];
            own0[l] = v0[l]; own1[l] = v1[l];
        }
        u2 = u1; u1 = u0; u0 = un;
        fcur = fn;
        softbar();
    };

    if (stripe == 0 || stripe == NS - 1) {
#pragma unroll 1
        for (int p = 0; p < STEPS; ++p) step(p, true);
    } else {
#pragma unroll 1
        for (int p = 0; p < FILLEND; ++p) step(p, true);
#pragma unroll 2
        for (int p = FILLEND; p < LOADCUT; ++p) step(p, false);
#pragma unroll 1
        for (int p = LOADCUT; p < STEPS; ++p) step(p, true);
    }
}

extern "C" void kernel_launch(void* const* d_in, const int* in_sizes, int n_in,
                              void* d_out, int out_size, void* d_ws, size_t ws_size,
                              hipStream_t stream)
{
    const float* x_in = (const float*)d_in[0];
    const float* f_in = (const float*)d_in[1];
    const float* k_in = (const float*)d_in[2];
    const float* u_in = (const float*)d_in[3];
    float* out = (float*)d_out;

    float* bufA = (float*)d_ws;                 // 64 MB field
    float* pmW0 = bufA + (size_t)BB * PLANE;
    float* pmW1 = pmW0 + BB * 16;
    float* pmZ  = pmW1 + BB * 16;
    float* taus = pmZ  + BB * 16;               // [15*BB]

    dim3 blk(256);

    // ---- 2 fused power passes, FD=10 @ R=64 (proven round-7 config) ----
    conv_fusedN<10, 64><<<dim3(8, BB), blk, 0, stream>>>(
        u_in, k_in, nullptr, bufA, pmW0, pmZ);
    conv_fusedN<10, 64><<<dim3(8, BB), blk, 0, stream>>>(
        bufA, k_in, pmW0, nullptr, pmW1, pmZ);

    tau_fused<<<BB, 64, 0, stream>>>(pmZ, pmW1, taus);

    // ---- 3 fused Chebyshev passes, FD=5 @ R=32 ----
    cheby9<5><<<dim3(16, BB), blk, 0, stream>>>(x_in, f_in, k_in, taus, out);
    cheby9<5><<<dim3(16, BB), blk, 0, stream>>>(out,  f_in, k_in, taus + 5 * BB, bufA);
    cheby9<5><<<dim3(16, BB), blk, 0, stream>>>(bufA, f_in, k_in, taus + 10 * BB, out);
}

// Round 10
// 395.948 us; speedup vs baseline: 1.2185x; 1.1372x over previous
//
#include <hip/hip_runtime.h>

#define BB 64
#define HH 512
#define WW 512
#define PLANE (HH * WW)
#define N_CHEBY 15

struct Sl { float a, b, c, d; };

__device__ __forceinline__ void racc(const Sl& s, float k0, float k1, float k2,
                                     float& o0, float& o1) {
    o0 = fmaf(k0, s.a, fmaf(k1, s.b, fmaf(k2, s.c, o0)));
    o1 = fmaf(k0, s.b, fmaf(k1, s.c, fmaf(k2, s.d, o1)));
}

__device__ __forceinline__ Sl ldsl(const float* pl, int row, int c2, bool ok) {
    Sl s = {0.f, 0.f, 0.f, 0.f};
    if (ok) {
        const float* rp = pl + (size_t)row * WW;
        float2 v = *reinterpret_cast<const float2*>(rp + c2);
        s.b = v.x; s.c = v.y;
        if (c2 > 0)      s.a = rp[c2 - 1];
        if (c2 + 2 < WW) s.d = rp[c2 + 2];
    }
    return s;
}

// Barrier WITHOUT vmcnt drain: flush LDS ops, leave global loads in flight.
__device__ __forceinline__ void softbar() {
    __asm__ volatile("s_waitcnt lgkmcnt(0)" ::: "memory");
    __builtin_amdgcn_s_barrier();
}

// ---------------------------------------------------------------------------
// Fused FDv-level power pass (row-march, stripe height RR). Proven round-9
// config: FD=10 @ RR=64, ~45 us/pass.
// v1 = inv*A(in), v_{j+1} = A(v_j); mz = stripe max|v_{FDv-1}|, mw = max|v_FDv|.
// ---------------------------------------------------------------------------
template<int FDv, int RR>
__global__ __launch_bounds__(256, 2) void conv_fusedN(
    const float* __restrict__ in, const float* __restrict__ kern,
    const float* __restrict__ pm_prev, float* __restrict__ out,
    float* __restrict__ pmw, float* __restrict__ pmz)
{
    constexpr int NS = HH / RR;
    const int b = blockIdx.y, stripe = blockIdx.x, ytop = stripe * RR;
    const int t = threadIdx.x, c2 = t << 1;

    __shared__ float re[FDv - 1][2][258], ro[FDv - 1][2][258];
    __shared__ float sred[8];
    __shared__ float sinv;

    if (t < 2 * (FDv - 1)) {
        const int l = t >> 1, par = t & 1;
        re[l][par][0] = 0.f; re[l][par][257] = 0.f;
        ro[l][par][0] = 0.f; ro[l][par][257] = 0.f;
    }
    if (pm_prev && t < 64) {
        float v = (t < NS) ? pm_prev[b * NS + t] : 0.f;
#pragma unroll
        for (int o = 8; o; o >>= 1) v = fmaxf(v, __shfl_xor(v, o, 64));
        if (t == 0) sinv = 1.f / v;
    }
    __syncthreads();
    const float invv = pm_prev ? sinv : 1.f;

    const float* kb = kern + b * 9;
    const float k00=kb[0],k01=kb[1],k02=kb[2],k10=kb[3],k11=kb[4],k12=kb[5],
                k20=kb[6],k21=kb[7],k22=kb[8];
    const float* ip = in + (size_t)b * PLANE;
    float* op = out ? out + (size_t)b * PLANE : nullptr;

    Sl u2 = {0,0,0,0}, u1 = {0,0,0,0};
    Sl ltp[FDv - 1], lmd[FDv - 1];
    float own0[FDv - 1], own1[FDv - 1];
#pragma unroll
    for (int l = 0; l < FDv - 1; ++l) {
        ltp[l] = Sl{0,0,0,0}; lmd[l] = Sl{0,0,0,0};
        own0[l] = 0.f; own1[l] = 0.f;
    }
    float mz = 0.f, mw = 0.f;
    Sl u0 = ldsl(ip, ytop - FDv, c2, (unsigned)(ytop - FDv) < HH);

    const int STEPS   = RR + 3 * FDv - 1;
    const int LOADCUT = RR + 2 * FDv - 1;
#pragma unroll 2
    for (int p = 0; p < STEPS; ++p) {
        const int yu = ytop - FDv + p;
        Sl un = ldsl(ip, yu + 1, c2, ((unsigned)(yu + 1) < HH) && (p < LOADCUT));

        const int rpar = (p + 1) & 1, wpar = p & 1;
        Sl am[FDv - 1];
#pragma unroll
        for (int l = 0; l < FDv - 1; ++l) {
            am[l].a = ro[l][rpar][t];
            am[l].b = own0[l];
            am[l].c = own1[l];
            am[l].d = re[l][rpar][2 + t];
        }

        float v0[FDv], v1[FDv];
        {   // level 1 (normalized)
            float s0 = 0.f, s1 = 0.f;
            racc(u2, k00,k01,k02, s0,s1);
            racc(u1, k10,k11,k12, s0,s1);
            racc(u0, k20,k21,k22, s0,s1);
            const int y = yu - 1;
            const bool act = (y >= ytop - (FDv-1)) && (y <= ytop + RR + FDv - 2)
                          && ((unsigned)y < HH);
            v0[0] = act ? s0 * invv : 0.f;
            v1[0] = act ? s1 * invv : 0.f;
        }
#pragma unroll
        for (int j = 2; j <= FDv; ++j) {
            float s0 = 0.f, s1 = 0.f;
            racc(ltp[j-2], k00,k01,k02, s0,s1);
            racc(lmd[j-2], k10,k11,k12, s0,s1);
            racc(am[j-2],  k20,k21,k22, s0,s1);
            const int y = yu - (2*j - 1);
            if (j < FDv) {
                const bool act = (y >= ytop - (FDv-j)) && (y <= ytop + RR + FDv - j - 1)
                              && ((unsigned)y < HH);
                v0[j-1] = act ? s0 : 0.f;
                v1[j-1] = act ? s1 : 0.f;
                if (j == FDv - 1)
                    mz = fmaxf(mz, fmaxf(fabsf(v0[j-1]), fabsf(v1[j-1])));
            } else {
                if (y >= ytop && y < ytop + RR) {
                    mw = fmaxf(mw, fmaxf(fabsf(s0), fabsf(s1)));
                    if (op)
                        *reinterpret_cast<float2*>(op + (size_t)y * WW + c2) =
                            make_float2(s0, s1);
                }
            }
        }
#pragma unroll
        for (int l = 0; l < FDv - 1; ++l) {
            re[l][wpar][1 + t] = v0[l];
            ro[l][wpar][1 + t] = v1[l];
            ltp[l] = lmd[l]; lmd[l] = am[l];
            own0[l] = v0[l]; own1[l] = v1[l];
        }
        u2 = u1; u1 = u0; u0 = un;
        softbar();
    }

#pragma unroll
    for (int o = 32; o; o >>= 1) {
        mz = fmaxf(mz, __shfl_xor(mz, o, 64));
        mw = fmaxf(mw, __shfl_xor(mw, o, 64));
    }
    if ((t & 63) == 0) { sred[t >> 6] = mz; sred[4 + (t >> 6)] = mw; }
    __syncthreads();
    if (t == 0) {
        pmz[b * NS + stripe] =
            fmaxf(fmaxf(sred[0], sred[1]), fmaxf(sred[2], sred[3]));
        pmw[b * NS + stripe] =
            fmaxf(fmaxf(sred[4], sred[5]), fmaxf(sred[6], sred[7]));
    }
}

// m = max|v20| / max|v19|; taus[it*BB+b].  (8 stripes from the conv passes)
__global__ __launch_bounds__(64) void tau_fused(
    const float* __restrict__ pmz, const float* __restrict__ pmw,
    float* __restrict__ taus)
{
    constexpr int NS = 8;
    const int b = blockIdx.x, t = threadIdx.x;
    float vz = (t < NS) ? pmz[b * NS + t] : 0.f;
    float vw = (t < NS) ? pmw[b * NS + t] : 0.f;
#pragma unroll
    for (int o = 8; o; o >>= 1) {
        vz = fmaxf(vz, __shfl_xor(vz, o, 64));
        vw = fmaxf(vw, __shfl_xor(vw, o, 64));
    }
    if (t < N_CHEBY) {
        const float m = vw / vz;
        const double rr = cos(M_PI * (2.0 * t + 1.0) / (2.0 * N_CHEBY));
        const float denom = m + m / 3.0f - (m / 3.0f - m) * (float)rr;
        taus[t * BB + b] = 2.0f / denom;
    }
}

// ---------------------------------------------------------------------------
// Fused FDv-level Chebyshev pass (round-6 proven structure, stripe height RR):
// x_j = x_{j-1} + tau_{j-1}*(f - A x_{j-1}); f in a (2FDv-1)-deep register
// ring (level j uses fh[2(j-1)]); separate conflict-free re/ro float rings.
// RR=16 doubles grid occupancy vs RR=32 (round-6 was grid-capped at 36%).
// ---------------------------------------------------------------------------
template<int FDv, int RR>
__global__ __launch_bounds__(256, 4) void cheby_fusedN(
    const float* __restrict__ xin, const float* __restrict__ fin,
    const float* __restrict__ kern, const float* __restrict__ tauv,
    float* __restrict__ xout)
{
    const int b = blockIdx.y, stripe = blockIdx.x, ytop = stripe * RR;
    const int t = threadIdx.x, c2 = t << 1;

    __shared__ float re[FDv - 1][2][258], ro[FDv - 1][2][258];

    if (t < 2 * (FDv - 1)) {
        const int l = t >> 1, par = t & 1;
        re[l][par][0] = 0.f; re[l][par][257] = 0.f;
        ro[l][par][0] = 0.f; ro[l][par][257] = 0.f;
    }
    __syncthreads();

    const float* kb = kern + b * 9;
    const float k00=kb[0],k01=kb[1],k02=kb[2],k10=kb[3],k11=kb[4],k12=kb[5],
                k20=kb[6],k21=kb[7],k22=kb[8];
    float tau[FDv];
#pragma unroll
    for (int j = 0; j < FDv; ++j) tau[j] = tauv[j * BB + b];

    const float* xp = xin + (size_t)b * PLANE;
    const float* fp = fin + (size_t)b * PLANE;
    float* op = xout + (size_t)b * PLANE;

    Sl u2 = {0,0,0,0}, u1 = {0,0,0,0};
    Sl ltp[FDv - 1], lmd[FDv - 1];
    float own0[FDv - 1], own1[FDv - 1];
#pragma unroll
    for (int l = 0; l < FDv - 1; ++l) {
        ltp[l] = Sl{0,0,0,0}; lmd[l] = Sl{0,0,0,0};
        own0[l] = 0.f; own1[l] = 0.f;
    }
    float2 fh[2 * FDv - 1];
#pragma unroll
    for (int k = 1; k < 2 * FDv - 1; ++k) fh[k] = make_float2(0.f, 0.f);

    Sl u0 = ldsl(xp, ytop - FDv, c2, (unsigned)(ytop - FDv) < HH);
    {
        const int yf = ytop - FDv - 1;
        fh[0] = ((unsigned)yf < HH)
            ? *reinterpret_cast<const float2*>(fp + (size_t)yf * WW + c2)
            : make_float2(0.f, 0.f);
    }

    const int STEPS   = RR + 3 * FDv - 1;
    const int LOADCUT = RR + 2 * FDv - 1;
#pragma unroll 2
    for (int p = 0; p < STEPS; ++p) {
        const int yu = ytop - FDv + p;
        const bool ldok = (p < LOADCUT);
        Sl un = ldsl(xp, yu + 1, c2, ((unsigned)(yu + 1) < HH) && ldok);
        const float2 fn = (((unsigned)yu < HH) && ldok)
            ? *reinterpret_cast<const float2*>(fp + (size_t)yu * WW + c2)
            : make_float2(0.f, 0.f);

        const int rpar = (p + 1) & 1, wpar = p & 1;
        Sl am[FDv - 1];
#pragma unroll
        for (int l = 0; l < FDv - 1; ++l) {
            am[l].a = ro[l][rpar][t];
            am[l].b = own0[l];
            am[l].c = own1[l];
            am[l].d = re[l][rpar][2 + t];
        }

        float v0[FDv], v1[FDv];
        {   // level 1: x1 = x + tau0*(f - A x)   at row yu-1
            float s0 = 0.f, s1 = 0.f;
            racc(u2, k00,k01,k02, s0,s1);
            racc(u1, k10,k11,k12, s0,s1);
            racc(u0, k20,k21,k22, s0,s1);
            const int y = yu - 1;
            const bool act = (y >= ytop - (FDv-1)) && (y <= ytop + RR + FDv - 2)
                          && ((unsigned)y < HH);
            v0[0] = act ? fmaf(tau[0], fh[0].x - s0, u1.b) : 0.f;
            v1[0] = act ? fmaf(tau[0], fh[0].y - s1, u1.c) : 0.f;
        }
#pragma unroll
        for (int j = 2; j <= FDv; ++j) {
            float s0 = 0.f, s1 = 0.f;
            racc(ltp[j-2], k00,k01,k02, s0,s1);
            racc(lmd[j-2], k10,k11,k12, s0,s1);
            racc(am[j-2],  k20,k21,k22, s0,s1);
            const int y = yu - (2*j - 1);
            const float2 fv = fh[2*(j-1)];
            if (j < FDv) {
                const bool act = (y >= ytop - (FDv-j)) && (y <= ytop + RR + FDv - j - 1)
                              && ((unsigned)y < HH);
                v0[j-1] = act ? fmaf(tau[j-1], fv.x - s0, lmd[j-2].b) : 0.f;
                v1[j-1] = act ? fmaf(tau[j-1], fv.y - s1, lmd[j-2].c) : 0.f;
            } else {
                if (y >= ytop && y < ytop + RR) {
                    const float o0 = fmaf(tau[FDv-1], fv.x - s0, lmd[j-2].b);
                    const float o1 = fmaf(tau[FDv-1], fv.y - s1, lmd[j-2].c);
                    *reinterpret_cast<float2*>(op + (size_t)y * WW + c2) =
                        make_float2(o0, o1);
                }
            }
        }
#pragma unroll
        for (int l = 0; l < FDv - 1; ++l) {
            re[l][wpar][1 + t] = v0[l];
            ro[l][wpar][1 + t] = v1[l];
            ltp[l] = lmd[l]; lmd[l] = am[l];
            own0[l] = v0[l]; own1[l] = v1[l];
        }
        u2 = u1; u1 = u0; u0 = un;
#pragma unroll
        for (int k = 2 * FDv - 2; k > 0; --k) fh[k] = fh[k - 1];
        fh[0] = fn;
        softbar();
    }
}

extern "C" void kernel_launch(void* const* d_in, const int* in_sizes, int n_in,
                              void* d_out, int out_size, void* d_ws, size_t ws_size,
                              hipStream_t stream)
{
    const float* x_in = (const float*)d_in[0];
    const float* f_in = (const float*)d_in[1];
    const float* k_in = (const float*)d_in[2];
    const float* u_in = (const float*)d_in[3];
    float* out = (float*)d_out;

    float* bufA = (float*)d_ws;                 // 64 MB field
    float* pmW0 = bufA + (size_t)BB * PLANE;
    float* pmW1 = pmW0 + BB * 16;
    float* pmZ  = pmW1 + BB * 16;
    float* taus = pmZ  + BB * 16;               // [15*BB]

    dim3 blk(256);

    // ---- 2 fused power passes, FD=10 @ R=64 (proven round-9 config) ----
    conv_fusedN<10, 64><<<dim3(8, BB), blk, 0, stream>>>(
        u_in, k_in, nullptr, bufA, pmW0, pmZ);
    conv_fusedN<10, 64><<<dim3(8, BB), blk, 0, stream>>>(
        bufA, k_in, pmW0, nullptr, pmW1, pmZ);

    tau_fused<<<BB, 64, 0, stream>>>(pmZ, pmW1, taus);

    // ---- 3 fused Chebyshev passes, FD=5 @ R=16 (grid 2048 -> 8 blocks/CU) ----
    cheby_fusedN<5, 16><<<dim3(32, BB), blk, 0, stream>>>(
        x_in, f_in, k_in, taus, out);
    cheby_fusedN<5, 16><<<dim3(32, BB), blk, 0, stream>>>(
        out,  f_in, k_in, taus + 5 * BB, bufA);
    cheby_fusedN<5, 16><<<dim3(32, BB), blk, 0, stream>>>(
        bufA, f_in, k_in, taus + 10 * BB, out);
}